// Round 2
// baseline (751.650 us; speedup 1.0000x reference)
//
#include <hip/hip_runtime.h>
#include <hip/hip_bf16.h>
#include <stdint.h>

typedef __attribute__((ext_vector_type(8))) short short8;
typedef __attribute__((ext_vector_type(4))) float f32x4;
typedef __attribute__((ext_vector_type(4))) int int4v;

#define LDS_ROW_BYTES 400  // 384 + 16B pad: keeps 16B alignment, breaks bank aliasing

__device__ __forceinline__ unsigned short f2bf(float f) {
    union { float f; uint32_t u; } v; v.f = f;
    return (unsigned short)((v.u + 0x7FFFu + ((v.u >> 16) & 1u)) >> 16);
}

// Build W[j][k] (bf16, row-major 192x192): W[h*16+oc][g*16+ic] = kernel[cayley[inv[g],h]][oc][ic]
__global__ void build_w_kernel(const float* __restrict__ kern,
                               const int* __restrict__ cayley,
                               const int* __restrict__ inv,
                               unsigned short* __restrict__ Wbf) {
    int i = blockIdx.x * blockDim.x + threadIdx.x;
    if (i >= 192 * 192) return;
    int j = i / 192;
    int k = i - j * 192;
    int h = j >> 4, oc = j & 15;
    int g = k >> 4, ic = k & 15;
    int cidx = cayley[inv[g] * 12 + h];
    Wbf[i] = f2bf(kern[cidx * 256 + oc * 16 + ic]);
}

// out[n][j] = sum_k x[n][k] * W[j][k] + bias[j & 15]
// 8 waves/block; W staged in LDS (padded rows); each wave grid-strides over
// 16-row strips with next-strip A prefetch issued before the compute phase.
__global__ __launch_bounds__(512, 4) void gemm_kernel(
    const float* __restrict__ x,
    const unsigned short* __restrict__ Wbf,
    const float* __restrict__ bias,
    float* __restrict__ out, int nstrips) {
  extern __shared__ unsigned char lds[];  // 192 * 400 = 76800 B
  const int tid  = threadIdx.x;
  const int lane = tid & 63;
  const int wid  = tid >> 6;
  const int l15  = lane & 15;
  const int lhi  = lane >> 4;

  // Stage W (bf16 192x192) into LDS with padded row stride.
  for (int idx = tid; idx < 192 * 24; idx += 512) {
    int row = idx / 24, o = idx - row * 24;
    int4v v = *(const int4v*)(Wbf + row * 192 + o * 8);
    *(int4v*)(lds + row * LDS_ROW_BYTES + o * 16) = v;
  }
  __syncthreads();

  const float bval = bias[l15];
  // B fragment base for this lane: addr(ct,c) = (ct*16+l15)*400 + c*64 + lhi*16
  const unsigned char* bbase = lds + l15 * LDS_ROW_BYTES + lhi * 16;

  const int gw      = blockIdx.x * 8 + wid;
  const int wstride = gridDim.x * 8;

  f32x4 araw[12];
  int strip = gw;
  if (strip < nstrips) {
    const float* xr = x + (size_t)(strip * 16 + l15) * 192 + lhi * 8;
    #pragma unroll
    for (int c = 0; c < 6; ++c) {
      araw[2 * c]     = *(const f32x4*)(xr + c * 32);
      araw[2 * c + 1] = *(const f32x4*)(xr + c * 32 + 4);
    }
  }

  while (strip < nstrips) {
    // Convert current strip's A to bf16 fragments.
    short8 abf[6];
    #pragma unroll
    for (int c = 0; c < 6; ++c) {
      short8 v;
      #pragma unroll
      for (int e = 0; e < 4; ++e) {
        v[e]     = (short)f2bf(araw[2 * c][e]);
        v[e + 4] = (short)f2bf(araw[2 * c + 1][e]);
      }
      abf[c] = v;
    }

    // Issue next strip's A loads (prefetch) before the compute phase.
    const int nxt = strip + wstride;
    if (nxt < nstrips) {
      const float* xr = x + (size_t)(nxt * 16 + l15) * 192 + lhi * 8;
      #pragma unroll
      for (int c = 0; c < 6; ++c) {
        araw[2 * c]     = *(const f32x4*)(xr + c * 32);
        araw[2 * c + 1] = *(const f32x4*)(xr + c * 32 + 4);
      }
    }

    float* obase = out + (size_t)(strip * 16 + lhi * 4) * 192 + l15;
    #pragma unroll
    for (int ct = 0; ct < 12; ++ct) {
      const unsigned char* br = bbase + ct * 16 * LDS_ROW_BYTES;
      f32x4 acc = {0.f, 0.f, 0.f, 0.f};
      #pragma unroll
      for (int c = 0; c < 6; ++c) {
        short8 b = *(const short8*)(br + c * 64);
        acc = __builtin_amdgcn_mfma_f32_16x16x32_bf16(abf[c], b, acc, 0, 0, 0);
      }
      // D: col = lane&15 (=l15), row = lhi*4 + r
      #pragma unroll
      for (int r = 0; r < 4; ++r)
        obase[(size_t)r * 192 + ct * 16] = acc[r] + bval;
    }
    strip = nxt;
  }
}

extern "C" void kernel_launch(void* const* d_in, const int* in_sizes, int n_in,
                              void* d_out, int out_size, void* d_ws, size_t ws_size,
                              hipStream_t stream) {
    const float* x      = (const float*)d_in[0];
    const float* kern   = (const float*)d_in[1];
    const float* bias   = (const float*)d_in[2];
    const int*   cayley = (const int*)d_in[3];
    const int*   inv    = (const int*)d_in[4];
    float* out = (float*)d_out;
    unsigned short* Wbf = (unsigned short*)d_ws;   // 192*192*2 = 73728 bytes

    const int nrows = in_sizes[0] / 192;
    const int nstrips = nrows / 16;

    build_w_kernel<<<(192 * 192 + 255) / 256, 256, 0, stream>>>(kern, cayley, inv, Wbf);

    gemm_kernel<<<512, 512, 192 * LDS_ROW_BYTES, stream>>>(x, Wbf, bias, out, nstrips);
}

// Round 3
// 358.263 us; speedup vs baseline: 2.0980x; 2.0980x over previous
//
#include <hip/hip_runtime.h>
#include <hip/hip_bf16.h>
#include <stdint.h>

typedef __attribute__((ext_vector_type(8))) short short8;
typedef __attribute__((ext_vector_type(4))) float f32x4;
typedef __attribute__((ext_vector_type(4))) int int4v;

#define LDS_ROW_BYTES 400  // 384 + 16B pad: keeps 16B alignment, breaks bank aliasing

__device__ __forceinline__ unsigned short f2bf(float f) {
    union { float f; uint32_t u; } v; v.f = f;
    return (unsigned short)((v.u + 0x7FFFu + ((v.u >> 16) & 1u)) >> 16);
}

// Build W[j][k] (bf16, row-major 192x192): W[h*16+oc][g*16+ic] = kernel[cayley[inv[g],h]][oc][ic]
__global__ void build_w_kernel(const float* __restrict__ kern,
                               const int* __restrict__ cayley,
                               const int* __restrict__ inv,
                               unsigned short* __restrict__ Wbf) {
    int i = blockIdx.x * blockDim.x + threadIdx.x;
    if (i >= 192 * 192) return;
    int j = i / 192;
    int k = i - j * 192;
    int h = j >> 4, oc = j & 15;
    int g = k >> 4, ic = k & 15;
    int cidx = cayley[inv[g] * 12 + h];
    Wbf[i] = f2bf(kern[cidx * 256 + oc * 16 + ic]);
}

// out[n][j] = sum_k x[n][k] * W[j][k] + bias[j & 15]
// 8 waves/block; W staged in LDS (padded rows); each wave grid-strides over
// 16-row strips with next-strip A prefetch issued before the compute phase.
// __launch_bounds__(512, 2): empirically caps VGPR at 128 (min-waves=4 capped
// at 64 and spilled ~1 GB of scratch in R1; 128 is spill-free per R0).
__global__ __launch_bounds__(512, 2) void gemm_kernel(
    const float* __restrict__ x,
    const unsigned short* __restrict__ Wbf,
    const float* __restrict__ bias,
    float* __restrict__ out, int nstrips) {
  extern __shared__ unsigned char lds[];  // 192 * 400 = 76800 B
  const int tid  = threadIdx.x;
  const int lane = tid & 63;
  const int wid  = tid >> 6;
  const int l15  = lane & 15;
  const int lhi  = lane >> 4;

  // Stage W (bf16 192x192) into LDS with padded row stride.
  for (int idx = tid; idx < 192 * 24; idx += 512) {
    int row = idx / 24, o = idx - row * 24;
    int4v v = *(const int4v*)(Wbf + row * 192 + o * 8);
    *(int4v*)(lds + row * LDS_ROW_BYTES + o * 16) = v;
  }
  __syncthreads();

  const float bval = bias[l15];
  // B fragment base for this lane: addr(ct,c) = (ct*16+l15)*400 + c*64 + lhi*16
  const unsigned char* bbase = lds + l15 * LDS_ROW_BYTES + lhi * 16;

  const int gw      = blockIdx.x * 8 + wid;
  const int wstride = gridDim.x * 8;

  f32x4 araw[12];
  int strip = gw;
  if (strip < nstrips) {
    const float* xr = x + (size_t)(strip * 16 + l15) * 192 + lhi * 8;
    #pragma unroll
    for (int c = 0; c < 6; ++c) {
      araw[2 * c]     = *(const f32x4*)(xr + c * 32);
      araw[2 * c + 1] = *(const f32x4*)(xr + c * 32 + 4);
    }
  }

  while (strip < nstrips) {
    // Convert current strip's A to bf16 fragments.
    short8 abf[6];
    #pragma unroll
    for (int c = 0; c < 6; ++c) {
      short8 v;
      #pragma unroll
      for (int e = 0; e < 4; ++e) {
        v[e]     = (short)f2bf(araw[2 * c][e]);
        v[e + 4] = (short)f2bf(araw[2 * c + 1][e]);
      }
      abf[c] = v;
    }

    // Issue next strip's A loads (prefetch) before the compute phase.
    const int nxt = strip + wstride;
    if (nxt < nstrips) {
      const float* xr = x + (size_t)(nxt * 16 + l15) * 192 + lhi * 8;
      #pragma unroll
      for (int c = 0; c < 6; ++c) {
        araw[2 * c]     = *(const f32x4*)(xr + c * 32);
        araw[2 * c + 1] = *(const f32x4*)(xr + c * 32 + 4);
      }
    }

    float* obase = out + (size_t)(strip * 16 + lhi * 4) * 192 + l15;
    #pragma unroll
    for (int ct = 0; ct < 12; ++ct) {
      const unsigned char* br = bbase + ct * 16 * LDS_ROW_BYTES;
      f32x4 acc = {0.f, 0.f, 0.f, 0.f};
      #pragma unroll
      for (int c = 0; c < 6; ++c) {
        short8 b = *(const short8*)(br + c * 64);
        acc = __builtin_amdgcn_mfma_f32_16x16x32_bf16(abf[c], b, acc, 0, 0, 0);
      }
      // D: col = lane&15 (=l15), row = lhi*4 + r
      #pragma unroll
      for (int r = 0; r < 4; ++r)
        obase[(size_t)r * 192 + ct * 16] = acc[r] + bval;
    }
    strip = nxt;
  }
}

extern "C" void kernel_launch(void* const* d_in, const int* in_sizes, int n_in,
                              void* d_out, int out_size, void* d_ws, size_t ws_size,
                              hipStream_t stream) {
    const float* x      = (const float*)d_in[0];
    const float* kern   = (const float*)d_in[1];
    const float* bias   = (const float*)d_in[2];
    const int*   cayley = (const int*)d_in[3];
    const int*   inv    = (const int*)d_in[4];
    float* out = (float*)d_out;
    unsigned short* Wbf = (unsigned short*)d_ws;   // 192*192*2 = 73728 bytes

    const int nrows = in_sizes[0] / 192;
    const int nstrips = nrows / 16;

    build_w_kernel<<<(192 * 192 + 255) / 256, 256, 0, stream>>>(kern, cayley, inv, Wbf);

    gemm_kernel<<<512, 512, 192 * LDS_ROW_BYTES, stream>>>(x, Wbf, bias, out, nstrips);
}